// Round 15
// baseline (289.840 us; speedup 1.0000x reference)
//
#include <hip/hip_runtime.h>
#include <hip/hip_bf16.h>
#include <cstdint>
#include <cstddef>

using s16x8 = __attribute__((ext_vector_type(8))) short;
using u16x8 = __attribute__((ext_vector_type(8))) unsigned short;
using f32x4 = __attribute__((ext_vector_type(4))) float;

#define GC 4096                        // G * c = 512*8
#define SCALE_G 0.04419417382415922f   // 1/sqrt(512)

__device__ __forceinline__ float gelu_f(float x) {
  float u = 0.7978845608028654f * (x + 0.044715f * x * x * x);
  return 0.5f * x * (1.0f + tanhf(u));
}

// fp32 -> bf16 bits, round-to-nearest-even
__device__ __forceinline__ unsigned short f2bf(float f) {
  unsigned int u = __float_as_uint(f);
  unsigned int r = (u + 0x7fffu + ((u >> 16) & 1u)) >> 16;
  return (unsigned short)r;
}
__device__ __forceinline__ float bf2f(unsigned short b) {
  return __uint_as_float(((unsigned int)b) << 16);
}

// Index arrays may arrive as int32 or int64 (JAX_ENABLE_X64). perms/mult row 0
// are identity [0,1,2,...]: int64 LE high words are 0. Low word suffices.
__device__ __forceinline__ int idx_stride(const int* __restrict__ identity_row) {
  return (identity_row[1] == 0 && identity_row[3] == 0 && identity_row[5] == 0) ? 2 : 1;
}

typedef __attribute__((address_space(1))) void gvoid;
typedef __attribute__((address_space(3))) void lvoid;
__device__ __forceinline__ void gld16(const void* g, void* l) {
  __builtin_amdgcn_global_load_lds((gvoid*)g, (lvoid*)l, 16, 0, 0);
}

// raw 16B global load into VGPRs; NO compiler-tracked wait — caller must
// guard every use behind a manual s_waitcnt vmcnt(N) before consumption.
__device__ __forceinline__ s16x8 gload16(const unsigned short* p) {
  s16x8 r;
  asm volatile("global_load_dwordx4 %0, %1, off" : "=v"(r) : "v"(p));
  return r;
}

// ---------------- fused prep: s->bf16, lift scatter, packed-T table, K^T ----
// TallP[w*512+g] (u32, w = kt*4+lq) = tv(h=kt*8+lq) | tv(h=kt*8+4+lq) << 16,
//   tv(h) = mult[g*512 + inv[h]]   (both ks halves of a K-tile in one word)
// K0T*[tgh*64 + d*8 + c] = bf16(K[tgh*64 + c*8 + d])  (d-major transpose)
__global__ __launch_bounds__(256) void k_prep(
    const float* __restrict__ s, const int* __restrict__ perms,
    const int* __restrict__ mult, const int* __restrict__ inv,
    const float* __restrict__ Wl, const float* __restrict__ K0,
    const float* __restrict__ K1,
    unsigned short* __restrict__ sb, unsigned short* __restrict__ WPT,
    unsigned int* __restrict__ TallP, unsigned short* __restrict__ K0T0,
    unsigned short* __restrict__ K0T1) {
  const int tid = blockIdx.x * 256 + threadIdx.x;
  if (tid < 65536) {                       // s -> bf16
    sb[tid] = f2bf(s[tid]);
  } else if (tid < 98304) {                // lift weight: WPT[(h*8+c)*64+perm]
    const int st = idx_stride(perms);
    const int t2 = tid - 65536;
    const int n = t2 & 63, h = t2 >> 6;
    const int m = perms[(size_t)t2 * st];
#pragma unroll
    for (int c = 0; c < 8; ++c)
      WPT[(size_t)((h << 3) + c) * 64 + m] = f2bf(Wl[n * 8 + c]);
  } else if (tid < 229376) {               // packed T table (131072 words)
    const int st = idx_stride(mult);
    const int i3 = tid - 98304;
    const int g = i3 & 511, w = i3 >> 9;   // w = kt*4 + lq
    const int h0 = (w >> 2) * 8 + (w & 3), h1 = h0 + 4;
    const int ih0 = inv[(size_t)h0 * st], ih1 = inv[(size_t)h1 * st];
    const unsigned int tv0 = (unsigned int)mult[(size_t)((g << 9) + ih0) * st];
    const unsigned int tv1 = (unsigned int)mult[(size_t)((g << 9) + ih1) * st];
    TallP[(size_t)w * 512 + g] = tv0 | (tv1 << 16);
  } else if (tid < 262144) {               // K0 d-transpose -> bf16
    const int t4 = tid - 229376;
    const int tgh = t4 >> 6, e = t4 & 63, d = e >> 3, c = e & 7;
    K0T0[tgh * 64 + d * 8 + c] = f2bf(K0[tgh * 64 + c * 8 + d]);
  } else if (tid < 294912) {               // K1 d-transpose -> bf16
    const int t5 = tid - 262144;
    const int tgh = t5 >> 6, e = t5 & 63, d = e >> 3, c = e & 7;
    K0T1[tgh * 64 + d * 8 + c] = f2bf(K1[tgh * 64 + c * 8 + d]);
  }
}

// ---------------- lift GEMM (K=64): staged-B path ---------------------------
__global__ __launch_bounds__(256) void gemm_bf16(
    const unsigned short* __restrict__ A,   // M x K, row-major bf16
    const unsigned short* __restrict__ BT,  // N x K, row-major bf16 (B^T)
    unsigned short* __restrict__ C,         // M x N bf16 out
    const float* __restrict__ bias8,        // 8 floats indexed by col&7, or null
    float scale, int M, int N, int K) {
  constexpr int BM = 64, BN = 128, BK = 64;
  __shared__ __align__(16) unsigned short As[3][BM * BK];
  __shared__ __align__(16) unsigned short Bs[3][BN * BK];

  const int nbm = M / BM;
  int bid = blockIdx.x;
  {
    const int q = (nbm * (N / BN)) >> 3;
    bid = (bid & 7) * q + (bid >> 3);
  }
  const int bn = bid / nbm, bm = bid % nbm;

  const int t = threadIdx.x;
  const int wid = t >> 6, lane = t & 63;
  const int wm = (wid >> 1) << 5;
  const int wn = (wid & 1) << 6;
  const int lr = lane & 15, lq = lane >> 4;

  const unsigned short* gA[2];
  const unsigned short* gB[4];
#pragma unroll
  for (int is = 0; is < 2; ++is) {
    const int sidx = is * 256 + t, row = sidx >> 3, c = (sidx & 7) ^ (row & 7);
    gA[is] = A + (size_t)(bm * BM + row) * K + c * 8;
  }
#pragma unroll
  for (int is = 0; is < 4; ++is) {
    const int sidx = is * 256 + t, row = sidx >> 3, c = (sidx & 7) ^ (row & 7);
    gB[is] = BT + (size_t)(bn * BN + row) * K + c * 8;
  }

  int aoff[2][2], boff[4][2];
#pragma unroll
  for (int i = 0; i < 2; ++i) {
    const int row = wm + i * 16 + lr;
#pragma unroll
    for (int ks = 0; ks < 2; ++ks)
      aoff[i][ks] = (row * 8 + ((ks * 4 + lq) ^ (row & 7))) * 16;
  }
#pragma unroll
  for (int j = 0; j < 4; ++j) {
    const int row = wn + j * 16 + lr;
#pragma unroll
    for (int ks = 0; ks < 2; ++ks)
      boff[j][ks] = (row * 8 + ((ks * 4 + lq) ^ (row & 7))) * 16;
  }

  auto stage = [&](int kt, int buf) {
    const int koff = kt * BK;
    char* la = (char*)&As[buf][0];
    char* lb = (char*)&Bs[buf][0];
#pragma unroll
    for (int is = 0; is < 2; ++is) gld16(gA[is] + koff, la + (is * 256 + t) * 16);
#pragma unroll
    for (int is = 0; is < 4; ++is) gld16(gB[is] + koff, lb + (is * 256 + t) * 16);
  };

  f32x4 acc[2][4] = {};
  const int nt = K / BK;
  stage(0, 0);
  if (nt > 1) stage(1, 1);

  int cur = 0;
  for (int kt = 0; kt < nt; ++kt) {
    if (kt < nt - 1) asm volatile("s_waitcnt vmcnt(6)" ::: "memory");
    else             asm volatile("s_waitcnt vmcnt(0)" ::: "memory");
    __builtin_amdgcn_s_barrier();
    asm volatile("" ::: "memory");
    __builtin_amdgcn_sched_barrier(0);
    if (kt + 2 < nt) {
      int nb = cur + 2; if (nb >= 3) nb -= 3;
      stage(kt + 2, nb);
    }
    const char* Ac = (const char*)&As[cur][0];
    const char* Bc = (const char*)&Bs[cur][0];
#pragma unroll
    for (int ks = 0; ks < 2; ++ks) {
      s16x8 a0 = *(const s16x8*)(Ac + aoff[0][ks]);
      s16x8 a1 = *(const s16x8*)(Ac + aoff[1][ks]);
      s16x8 b0 = *(const s16x8*)(Bc + boff[0][ks]);
      s16x8 b1 = *(const s16x8*)(Bc + boff[1][ks]);
      s16x8 b2 = *(const s16x8*)(Bc + boff[2][ks]);
      s16x8 b3 = *(const s16x8*)(Bc + boff[3][ks]);
      acc[0][0] = __builtin_amdgcn_mfma_f32_16x16x32_bf16(a0, b0, acc[0][0], 0, 0, 0);
      acc[0][1] = __builtin_amdgcn_mfma_f32_16x16x32_bf16(a0, b1, acc[0][1], 0, 0, 0);
      acc[0][2] = __builtin_amdgcn_mfma_f32_16x16x32_bf16(a0, b2, acc[0][2], 0, 0, 0);
      acc[0][3] = __builtin_amdgcn_mfma_f32_16x16x32_bf16(a0, b3, acc[0][3], 0, 0, 0);
      acc[1][0] = __builtin_amdgcn_mfma_f32_16x16x32_bf16(a1, b0, acc[1][0], 0, 0, 0);
      acc[1][1] = __builtin_amdgcn_mfma_f32_16x16x32_bf16(a1, b1, acc[1][1], 0, 0, 0);
      acc[1][2] = __builtin_amdgcn_mfma_f32_16x16x32_bf16(a1, b2, acc[1][2], 0, 0, 0);
      acc[1][3] = __builtin_amdgcn_mfma_f32_16x16x32_bf16(a1, b3, acc[1][3], 0, 0, 0);
    }
    cur = (cur == 2) ? 0 : cur + 1;
  }

#pragma unroll
  for (int i = 0; i < 2; ++i) {
    const int row0 = bm * BM + wm + i * 16 + lq * 4;
#pragma unroll
    for (int j = 0; j < 4; ++j) {
      const int col = bn * BN + wn + j * 16 + lr;
      const float bv = bias8 ? bias8[col & 7] : 0.0f;
#pragma unroll
      for (int r = 0; r < 4; ++r) {
        float v = gelu_f(acc[i][j][r] * scale + bv);
        C[(size_t)(row0 + r) * N + col] = f2bf(v);
      }
    }
  }
}

// ---------------- fused group-conv GEMM v10: barrier-free, all-register -----
// R12/R13/R14 closed the matrix: no data pipe is the limiter -- the per-phase
// barrier/lockstep skeleton is (~950 cyc/phase regardless of work). So: NO
// LDS staging for A; each wave gathers its own A fragments per-lane from
// global (A panel 1 MB, L2-resident per XCD; every 16-line instruction's
// 64B lines are 100% consumed: 4 lanes x 16B). B from K0T as before. tv from
// a 16 KB LDS TlP loaded once (the kernel's ONLY barrier). Zero barriers in
// the 64-tile main loop; each wave runs an independent 2-deep register
// pipeline; waves drift freely and mix pipes naturally.
// Geometry: block 128x128, grid 256 (bm=bid&7), 512 thr = 8 waves 2(wm)x4(wn),
// wave-tile 64x32 (acc[4][2], 16 MFMA/tile).
// Pipeline: at iter kt issue tile kt+1's 12 loads (8 A + 4 B), then
// vmcnt(12) certifies tile kt's 12 (issued last iter), sched_barrier,
// setprio(1), 16 MFMA. Tail kt=NT-1: vmcnt(0). Register parity double-buffer
// with static names (rule #20).
__global__ __launch_bounds__(512, 2) void gemm_fused(
    const unsigned short* __restrict__ A,     // 1024 x 4096 bf16
    const unsigned short* __restrict__ K0T,   // 512 x 64 bf16 (d-major)
    const unsigned int* __restrict__ TallP,   // [kt*4+lq][g] packed u32
    unsigned short* __restrict__ C,           // 1024 x 4096 bf16
    float scale) {
  constexpr int Kdim = 4096, N = 4096, BM = 128, NT = 64;
  __shared__ __align__(16) unsigned int TlP[64 * 4 * 16];  // 16 KB

  const int bm = blockIdx.x & 7;    // XCD x owns A-panel bm=x (1 MB, L2-fit)
  const int bn = blockIdx.x >> 3;   // 0..31

  const int t = threadIdx.x;               // 0..511
  const int wid = t >> 6, lane = t & 63;
  const int wm = (wid >> 2) << 6;          // 0,64
  const int wn = (wid & 3) << 5;           // 0,32,64,96
  const int lr = lane & 15, lq = lane >> 4;
  const int glb = (wn >> 3) + (lr >> 3);   // block-local g base
  const int dlo = lr & 7;

  // per-lane A gather bases (i, ks); tile kt adds kt*64 elements (128 B)
  const unsigned short* gAF[4][2];
#pragma unroll
  for (int i = 0; i < 4; ++i)
#pragma unroll
    for (int ks = 0; ks < 2; ++ks)
      gAF[i][ks] = A + (size_t)(bm * BM + wm + i * 16 + lr) * Kdim +
                   (ks * 4 + lq) * 8;

  // prologue: TlP (2 gld16/thread) -> the kernel's only barrier
#pragma unroll
  for (int is = 0; is < 2; ++is) {
    const int sidx = is * 512 + t;                  // 0..1023 slots
    const unsigned int* src =
        TallP + (size_t)(sidx >> 2) * 512 + bn * 16 + (sidx & 3) * 4;
    gld16(src, (char*)&TlP[0] + sidx * 16);
  }
  asm volatile("s_waitcnt vmcnt(0)" ::: "memory");
  __builtin_amdgcn_s_barrier();
  asm volatile("" ::: "memory");

  f32x4 acc[4][2] = {};
  s16x8 aA[4][2], aB[4][2];    // A-frag regs, per-tile parity
  s16x8 bA[2][2], bB[2][2];    // B regs, per-tile parity
  unsigned int tvA[2], tvB[2]; // packed tv, one tile ahead of its B issue

  // prologue: tv(0), tv(1); issue tile0 loads (8 A + 4 B = 12)
  {
    unsigned int tv0[2];
#pragma unroll
    for (int j = 0; j < 2; ++j) tv0[j] = TlP[(0 * 4 + lq) * 16 + glb + j * 2];
#pragma unroll
    for (int j = 0; j < 2; ++j) tvA[j] = TlP[(1 * 4 + lq) * 16 + glb + j * 2];
#pragma unroll
    for (int i = 0; i < 4; ++i)
#pragma unroll
      for (int ks = 0; ks < 2; ++ks) aA[i][ks] = gload16(gAF[i][ks]);
#pragma unroll
    for (int j = 0; j < 2; ++j) {
      bA[j][0] = gload16(K0T + (tv0[j] & 0xFFFFu) * 64 + dlo * 8);
      bA[j][1] = gload16(K0T + (tv0[j] >> 16) * 64 + dlo * 8);
    }
  }

  auto iter = [&](int kt, s16x8 (&aC)[4][2], s16x8 (&aN)[4][2],
                  s16x8 (&bC)[2][2], s16x8 (&bN)[2][2],
                  unsigned int (&tvC)[2], unsigned int (&tvN)[2]) {
    if (kt + 2 < NT) {  // tv(kt+2) for next iter's B issue
#pragma unroll
      for (int j = 0; j < 2; ++j)
        tvN[j] = TlP[((kt + 2) * 4 + lq) * 16 + glb + j * 2];
    }
    if (kt + 1 < NT) {  // issue tile kt+1: 8 A + 4 B
      const int koff = (kt + 1) * 64;
#pragma unroll
      for (int i = 0; i < 4; ++i)
#pragma unroll
        for (int ks = 0; ks < 2; ++ks) aN[i][ks] = gload16(gAF[i][ks] + koff);
#pragma unroll
      for (int j = 0; j < 2; ++j) {
        bN[j][0] = gload16(K0T + (tvC[j] & 0xFFFFu) * 64 + dlo * 8);
        bN[j][1] = gload16(K0T + (tvC[j] >> 16) * 64 + dlo * 8);
      }
      asm volatile("s_waitcnt vmcnt(12)" ::: "memory");  // tile kt landed
    } else {
      asm volatile("s_waitcnt vmcnt(0)" ::: "memory");
    }
    __builtin_amdgcn_sched_barrier(0);
    __builtin_amdgcn_s_setprio(1);
#pragma unroll
    for (int ks = 0; ks < 2; ++ks)
#pragma unroll
      for (int i = 0; i < 4; ++i) {
        acc[i][0] = __builtin_amdgcn_mfma_f32_16x16x32_bf16(aC[i][ks], bC[0][ks],
                                                            acc[i][0], 0, 0, 0);
        acc[i][1] = __builtin_amdgcn_mfma_f32_16x16x32_bf16(aC[i][ks], bC[1][ks],
                                                            acc[i][1], 0, 0, 0);
      }
    __builtin_amdgcn_s_setprio(0);
  };

  for (int kt2 = 0; kt2 < NT; kt2 += 2) {  // NT=64 even
    iter(kt2,     aA, aB, bA, bB, tvA, tvB);
    iter(kt2 + 1, aB, aA, bB, bA, tvB, tvA);
  }

  // epilogue: D row = lq*4+r (A-side), col = lr (B-side)  [m89-verified]
#pragma unroll
  for (int i = 0; i < 4; ++i) {
    const int row0 = bm * BM + wm + i * 16 + lq * 4;
#pragma unroll
    for (int j = 0; j < 2; ++j) {
      const int col = bn * 128 + wn + j * 16 + lr;
#pragma unroll
      for (int r = 0; r < 4; ++r) {
        float v = gelu_f(acc[i][j][r] * scale);
        C[(size_t)(row0 + r) * N + col] = f2bf(v);
      }
    }
  }
}

// ---------------- pool + head ----------------

__global__ __launch_bounds__(256) void k_pool(const unsigned short* __restrict__ X3,
                                              float* __restrict__ pooled) {
  __shared__ float part[256];
  const int b = blockIdx.x, t = threadIdx.x;
  const unsigned short* row = X3 + (size_t)b * GC;
  float a = 0.f;
#pragma unroll
  for (int i = 0; i < 16; ++i) a += bf2f(row[t + 256 * i]);
  part[t] = a;
  __syncthreads();
  if (t < 8) {
    float s = 0.f;
    for (int k = 0; k < 32; ++k) s += part[t + 8 * k];
    pooled[b * 8 + t] = s * (1.0f / 512.0f);
  }
}

// Harness compares flat float32 [0..1023] against ref amp (phase==0).
__global__ __launch_bounds__(256) void k_head(const float* __restrict__ pooled,
                                              const float* __restrict__ Wamp,
                                              const float* __restrict__ bamp,
                                              const float* __restrict__ Wph,
                                              const float* __restrict__ bph,
                                              float* __restrict__ out,
                                              int out_size) {
  int b = blockIdx.x * 256 + threadIdx.x;  // 1024
  if (b >= 1024) return;
  float a = bamp[0], p = bph[0];
#pragma unroll
  for (int d = 0; d < 8; ++d) {
    float v = pooled[b * 8 + d];
    a += v * Wamp[d];
    p += v * Wph[d];
  }
  out[b] = a;
  if (out_size >= 2048) out[1024 + b] = p;
}

// ---------------- launch ----------------

extern "C" void kernel_launch(void* const* d_in, const int* in_sizes, int n_in,
                              void* d_out, int out_size, void* d_ws, size_t ws_size,
                              hipStream_t stream) {
  (void)in_sizes; (void)n_in; (void)ws_size;
  const float* s    = (const float*)d_in[0];
  const int*   perms= (const int*)d_in[1];
  const int*   mult = (const int*)d_in[2];
  const int*   inv  = (const int*)d_in[3];
  const float* Wl   = (const float*)d_in[4];
  const float* bl   = (const float*)d_in[5];
  const float* K0   = (const float*)d_in[6];
  const float* K1   = (const float*)d_in[7];
  const float* Wamp = (const float*)d_in[8];
  const float* bamp = (const float*)d_in[9];
  const float* Wph  = (const float*)d_in[10];
  const float* bph  = (const float*)d_in[11];
  float* out = (float*)d_out;

  // workspace (~17.3 MB):
  //  X1 [0,8M)  X2 [8M,16M)  X3 = X1 overlay
  //  sb 16M+0..128K  WPT +128K..640K  TallP +640K..1152K
  //  K0T0 +1152K..1216K  K0T1 +1216K..1280K  pooled +1280K..1312K
  char* ws = (char*)d_ws;
  unsigned short* X1  = (unsigned short*)(ws);
  unsigned short* X2  = (unsigned short*)(ws + (8u << 20));
  unsigned short* X3  = X1;  // overlay (X1 dead after conv1)
  unsigned short* sb  = (unsigned short*)(ws + (16u << 20));
  unsigned short* WPT = (unsigned short*)(ws + (16u << 20) + (128u << 10));
  unsigned int*   TallP=(unsigned int*) (ws + (16u << 20) + (640u << 10));
  unsigned short* K0T0= (unsigned short*)(ws + (16u << 20) + (1152u << 10));
  unsigned short* K0T1= (unsigned short*)(ws + (16u << 20) + (1216u << 10));
  float* pooled       = (float*)(ws + (16u << 20) + (1280u << 10));

  k_prep<<<1152, 256, 0, stream>>>(s, perms, mult, inv, Wl, K0, K1,
                                   sb, WPT, TallP, K0T0, K0T1);
  // lift: X1 = gelu(s @ W_lift + b_lift), GEMM K=64
  gemm_bf16<<<512, 256, 0, stream>>>(sb, WPT, X1, bl, 1.0f, 1024, 4096, 64);
  gemm_fused<<<256, 512, 0, stream>>>(X1, K0T0, TallP, X2, SCALE_G);
  gemm_fused<<<256, 512, 0, stream>>>(X2, K0T1, TallP, X3, SCALE_G);
  k_pool<<<1024, 256, 0, stream>>>(X3, pooled);
  k_head<<<4, 256, 0, stream>>>(pooled, Wamp, bamp, Wph, bph, out, out_size);
}

// Round 16
// 132.121 us; speedup vs baseline: 2.1937x; 2.1937x over previous
//
#include <hip/hip_runtime.h>
#include <hip/hip_bf16.h>
#include <cstdint>
#include <cstddef>

using s16x8 = __attribute__((ext_vector_type(8))) short;
using u16x8 = __attribute__((ext_vector_type(8))) unsigned short;
using f32x4 = __attribute__((ext_vector_type(4))) float;

#define GC 4096                        // G * c = 512*8
#define SCALE_G 0.04419417382415922f   // 1/sqrt(512)

__device__ __forceinline__ float gelu_f(float x) {
  float u = 0.7978845608028654f * (x + 0.044715f * x * x * x);
  return 0.5f * x * (1.0f + tanhf(u));
}

// fp32 -> bf16 bits, round-to-nearest-even
__device__ __forceinline__ unsigned short f2bf(float f) {
  unsigned int u = __float_as_uint(f);
  unsigned int r = (u + 0x7fffu + ((u >> 16) & 1u)) >> 16;
  return (unsigned short)r;
}
__device__ __forceinline__ float bf2f(unsigned short b) {
  return __uint_as_float(((unsigned int)b) << 16);
}

// Index arrays may arrive as int32 or int64 (JAX_ENABLE_X64). perms/mult row 0
// are identity [0,1,2,...]: int64 LE high words are 0. Low word suffices.
__device__ __forceinline__ int idx_stride(const int* __restrict__ identity_row) {
  return (identity_row[1] == 0 && identity_row[3] == 0 && identity_row[5] == 0) ? 2 : 1;
}

typedef __attribute__((address_space(1))) void gvoid;
typedef __attribute__((address_space(3))) void lvoid;
__device__ __forceinline__ void gld16(const void* g, void* l) {
  __builtin_amdgcn_global_load_lds((gvoid*)g, (lvoid*)l, 16, 0, 0);
}

// raw 16B global load into VGPRs; NO compiler-tracked wait — caller must
// guard every use behind a manual s_waitcnt vmcnt(N) before consumption.
__device__ __forceinline__ s16x8 gload16(const unsigned short* p) {
  s16x8 r;
  asm volatile("global_load_dwordx4 %0, %1, off" : "=v"(r) : "v"(p));
  return r;
}

// ---------------- fused prep: s->bf16, lift scatter, packed-T table, K^T ----
// TallP[w*512+g] (u32, w = kt*4+lq) = tv(h=kt*8+lq) | tv(h=kt*8+4+lq) << 16,
//   tv(h) = mult[g*512 + inv[h]]   (both ks halves of a K-tile in one word)
// K0T*[tgh*64 + d*8 + c] = bf16(K[tgh*64 + c*8 + d])  (d-major transpose)
__global__ __launch_bounds__(256) void k_prep(
    const float* __restrict__ s, const int* __restrict__ perms,
    const int* __restrict__ mult, const int* __restrict__ inv,
    const float* __restrict__ Wl, const float* __restrict__ K0,
    const float* __restrict__ K1,
    unsigned short* __restrict__ sb, unsigned short* __restrict__ WPT,
    unsigned int* __restrict__ TallP, unsigned short* __restrict__ K0T0,
    unsigned short* __restrict__ K0T1) {
  const int tid = blockIdx.x * 256 + threadIdx.x;
  if (tid < 65536) {                       // s -> bf16
    sb[tid] = f2bf(s[tid]);
  } else if (tid < 98304) {                // lift weight: WPT[(h*8+c)*64+perm]
    const int st = idx_stride(perms);
    const int t2 = tid - 65536;
    const int n = t2 & 63, h = t2 >> 6;
    const int m = perms[(size_t)t2 * st];
#pragma unroll
    for (int c = 0; c < 8; ++c)
      WPT[(size_t)((h << 3) + c) * 64 + m] = f2bf(Wl[n * 8 + c]);
  } else if (tid < 229376) {               // packed T table (131072 words)
    const int st = idx_stride(mult);
    const int i3 = tid - 98304;
    const int g = i3 & 511, w = i3 >> 9;   // w = kt*4 + lq
    const int h0 = (w >> 2) * 8 + (w & 3), h1 = h0 + 4;
    const int ih0 = inv[(size_t)h0 * st], ih1 = inv[(size_t)h1 * st];
    const unsigned int tv0 = (unsigned int)mult[(size_t)((g << 9) + ih0) * st];
    const unsigned int tv1 = (unsigned int)mult[(size_t)((g << 9) + ih1) * st];
    TallP[(size_t)w * 512 + g] = tv0 | (tv1 << 16);
  } else if (tid < 262144) {               // K0 d-transpose -> bf16
    const int t4 = tid - 229376;
    const int tgh = t4 >> 6, e = t4 & 63, d = e >> 3, c = e & 7;
    K0T0[tgh * 64 + d * 8 + c] = f2bf(K0[tgh * 64 + c * 8 + d]);
  } else if (tid < 294912) {               // K1 d-transpose -> bf16
    const int t5 = tid - 262144;
    const int tgh = t5 >> 6, e = t5 & 63, d = e >> 3, c = e & 7;
    K0T1[tgh * 64 + d * 8 + c] = f2bf(K1[tgh * 64 + c * 8 + d]);
  }
}

// ---------------- lift GEMM (K=64): staged-B path ---------------------------
__global__ __launch_bounds__(256) void gemm_bf16(
    const unsigned short* __restrict__ A,   // M x K, row-major bf16
    const unsigned short* __restrict__ BT,  // N x K, row-major bf16 (B^T)
    unsigned short* __restrict__ C,         // M x N bf16 out
    const float* __restrict__ bias8,        // 8 floats indexed by col&7, or null
    float scale, int M, int N, int K) {
  constexpr int BM = 64, BN = 128, BK = 64;
  __shared__ __align__(16) unsigned short As[3][BM * BK];
  __shared__ __align__(16) unsigned short Bs[3][BN * BK];

  const int nbm = M / BM;
  int bid = blockIdx.x;
  {
    const int q = (nbm * (N / BN)) >> 3;
    bid = (bid & 7) * q + (bid >> 3);
  }
  const int bn = bid / nbm, bm = bid % nbm;

  const int t = threadIdx.x;
  const int wid = t >> 6, lane = t & 63;
  const int wm = (wid >> 1) << 5;
  const int wn = (wid & 1) << 6;
  const int lr = lane & 15, lq = lane >> 4;

  const unsigned short* gA[2];
  const unsigned short* gB[4];
#pragma unroll
  for (int is = 0; is < 2; ++is) {
    const int sidx = is * 256 + t, row = sidx >> 3, c = (sidx & 7) ^ (row & 7);
    gA[is] = A + (size_t)(bm * BM + row) * K + c * 8;
  }
#pragma unroll
  for (int is = 0; is < 4; ++is) {
    const int sidx = is * 256 + t, row = sidx >> 3, c = (sidx & 7) ^ (row & 7);
    gB[is] = BT + (size_t)(bn * BN + row) * K + c * 8;
  }

  int aoff[2][2], boff[4][2];
#pragma unroll
  for (int i = 0; i < 2; ++i) {
    const int row = wm + i * 16 + lr;
#pragma unroll
    for (int ks = 0; ks < 2; ++ks)
      aoff[i][ks] = (row * 8 + ((ks * 4 + lq) ^ (row & 7))) * 16;
  }
#pragma unroll
  for (int j = 0; j < 4; ++j) {
    const int row = wn + j * 16 + lr;
#pragma unroll
    for (int ks = 0; ks < 2; ++ks)
      boff[j][ks] = (row * 8 + ((ks * 4 + lq) ^ (row & 7))) * 16;
  }

  auto stage = [&](int kt, int buf) {
    const int koff = kt * BK;
    char* la = (char*)&As[buf][0];
    char* lb = (char*)&Bs[buf][0];
#pragma unroll
    for (int is = 0; is < 2; ++is) gld16(gA[is] + koff, la + (is * 256 + t) * 16);
#pragma unroll
    for (int is = 0; is < 4; ++is) gld16(gB[is] + koff, lb + (is * 256 + t) * 16);
  };

  f32x4 acc[2][4] = {};
  const int nt = K / BK;
  stage(0, 0);
  if (nt > 1) stage(1, 1);

  int cur = 0;
  for (int kt = 0; kt < nt; ++kt) {
    if (kt < nt - 1) asm volatile("s_waitcnt vmcnt(6)" ::: "memory");
    else             asm volatile("s_waitcnt vmcnt(0)" ::: "memory");
    __builtin_amdgcn_s_barrier();
    asm volatile("" ::: "memory");
    __builtin_amdgcn_sched_barrier(0);
    if (kt + 2 < nt) {
      int nb = cur + 2; if (nb >= 3) nb -= 3;
      stage(kt + 2, nb);
    }
    const char* Ac = (const char*)&As[cur][0];
    const char* Bc = (const char*)&Bs[cur][0];
#pragma unroll
    for (int ks = 0; ks < 2; ++ks) {
      s16x8 a0 = *(const s16x8*)(Ac + aoff[0][ks]);
      s16x8 a1 = *(const s16x8*)(Ac + aoff[1][ks]);
      s16x8 b0 = *(const s16x8*)(Bc + boff[0][ks]);
      s16x8 b1 = *(const s16x8*)(Bc + boff[1][ks]);
      s16x8 b2 = *(const s16x8*)(Bc + boff[2][ks]);
      s16x8 b3 = *(const s16x8*)(Bc + boff[3][ks]);
      acc[0][0] = __builtin_amdgcn_mfma_f32_16x16x32_bf16(a0, b0, acc[0][0], 0, 0, 0);
      acc[0][1] = __builtin_amdgcn_mfma_f32_16x16x32_bf16(a0, b1, acc[0][1], 0, 0, 0);
      acc[0][2] = __builtin_amdgcn_mfma_f32_16x16x32_bf16(a0, b2, acc[0][2], 0, 0, 0);
      acc[0][3] = __builtin_amdgcn_mfma_f32_16x16x32_bf16(a0, b3, acc[0][3], 0, 0, 0);
      acc[1][0] = __builtin_amdgcn_mfma_f32_16x16x32_bf16(a1, b0, acc[1][0], 0, 0, 0);
      acc[1][1] = __builtin_amdgcn_mfma_f32_16x16x32_bf16(a1, b1, acc[1][1], 0, 0, 0);
      acc[1][2] = __builtin_amdgcn_mfma_f32_16x16x32_bf16(a1, b2, acc[1][2], 0, 0, 0);
      acc[1][3] = __builtin_amdgcn_mfma_f32_16x16x32_bf16(a1, b3, acc[1][3], 0, 0, 0);
    }
    cur = (cur == 2) ? 0 : cur + 1;
  }

#pragma unroll
  for (int i = 0; i < 2; ++i) {
    const int row0 = bm * BM + wm + i * 16 + lq * 4;
#pragma unroll
    for (int j = 0; j < 4; ++j) {
      const int col = bn * BN + wn + j * 16 + lr;
      const float bv = bias8 ? bias8[col & 7] : 0.0f;
#pragma unroll
      for (int r = 0; r < 4; ++r) {
        float v = gelu_f(acc[i][j][r] * scale + bv);
        C[(size_t)(row0 + r) * N + col] = f2bf(v);
      }
    }
  }
}

// ---------------- fused group-conv GEMM v11: R11 + 1 barrier/tile -----------
// Geometry = R11 (grid 256, 512 thr, 8 waves 2x4, BM=128 BK=64, A 3-buf LDS
// 48KB + TlP 16KB, B per-lane global gather). Schedule: ONE phase per tile:
//   {vmcnt(0) | barrier | read A(kt+1) frags (8 ds_read) + issue B(kt+1) +
//    stage(kt+2) | sched_barrier | setprio(1) 16xMFMA(kt) setprio(0)}
// vmcnt(0) is free in steady state: at the wait the only outstanding ops are
// B(kt)+stage(kt+1), issued a FULL TILE earlier. Hazards: stage(kt+2) targets
// buf[(kt-1)%3] whose last ds_reads were consumed by MFMA(kt-1) (per-wave
// lgkm wait) before this barrier; stage(kt+1) visibility = own vmcnt drain +
// barrier (all waves), as in R11.
// POOL=0: write C (gelu, bf16). POOL=1: fused mean-pool — per-wave reduce over
// j and the lr<->lr^8 pair (d = col&7 = lr&7), plain store of per-plane
// partials to Ppart[128][1024][8] (each cell written exactly once ->
// deterministic, no atomics); k_head sums the 128 planes.
template <int POOL>
__global__ __launch_bounds__(512, 2) void gemm_fused(
    const unsigned short* __restrict__ A,     // 1024 x 4096 bf16
    const unsigned short* __restrict__ K0T,   // 512 x 64 bf16 (d-major)
    const unsigned int* __restrict__ TallP,   // [kt*4+lq][g] packed u32
    unsigned short* __restrict__ C,           // POOL=0 out
    float* __restrict__ Ppart,                // POOL=1 out [128][1024][8]
    float scale) {
  constexpr int Kdim = 4096, N = 4096, BM = 128, BK = 64, NT = Kdim / BK;
  __shared__ __align__(16) unsigned short As[3][BM * BK];  // 48 KB
  __shared__ __align__(16) unsigned int TlP[64 * 4 * 16];  // 16 KB

  const int bm = blockIdx.x & 7;    // XCD x owns A-panel bm=x (1 MB, L2-fit)
  const int bn = blockIdx.x >> 3;   // 0..31

  const int t = threadIdx.x;               // 0..511
  const int wid = t >> 6, lane = t & 63;
  const int wm = (wid >> 2) << 6;          // 0,64
  const int wn = (wid & 3) << 5;           // 0,32,64,96 (distinct per wave)
  const int lr = lane & 15, lq = lane >> 4;
  const int glb = (wn >> 3) + (lr >> 3);   // block-local g base
  const int dlo = lr & 7;

  // A staging source map (pre-swizzled: LDS slot s holds chunk (s&7)^(row&7))
  const unsigned short* gA[2];
#pragma unroll
  for (int is = 0; is < 2; ++is) {
    const int sidx = is * 512 + t, row = sidx >> 3, c = (sidx & 7) ^ (row & 7);
    gA[is] = A + (size_t)(bm * BM + row) * Kdim + c * 8;
  }
  auto stage = [&](int kt, int buf) {  // 2 gld16 / thread (16 KB tile)
    const int koff = kt * BK;
    char* la = (char*)&As[buf][0];
#pragma unroll
    for (int is = 0; is < 2; ++is) gld16(gA[is] + koff, la + (is * 512 + t) * 16);
  };

  int aoff[4][2];
#pragma unroll
  for (int i = 0; i < 4; ++i) {
    const int row = wm + i * 16 + lr;
#pragma unroll
    for (int ks = 0; ks < 2; ++ks)
      aoff[i][ks] = (row * 8 + ((ks * 4 + lq) ^ (row & 7))) * 16;
  }

  // prologue: stage(0), TlP (2 gld16), stage(1); full drain + barrier
  stage(0, 0);
#pragma unroll
  for (int is = 0; is < 2; ++is) {
    const int sidx = is * 512 + t;                  // 0..1023 slots
    const unsigned int* src =
        TallP + (size_t)(sidx >> 2) * 512 + bn * 16 + (sidx & 3) * 4;
    gld16(src, (char*)&TlP[0] + sidx * 16);
  }
  stage(1, 1);
  asm volatile("s_waitcnt vmcnt(0)" ::: "memory");
  __builtin_amdgcn_s_barrier();
  asm volatile("" ::: "memory");

  f32x4 acc[4][2] = {};
  s16x8 aA[4][2], aB[4][2];    // A-frag regs, per-tile parity
  s16x8 bA[2][2], bB[2][2];    // B regs, per-tile parity
  unsigned int tvA[2], tvB[2]; // packed tv, per-tile parity (read 1 tile early)

  // tv(0) fresh + tv(1) into tvA; B(0) into bA; aA <- A(0) (both ks)
  {
    unsigned int tv0[2];
#pragma unroll
    for (int j = 0; j < 2; ++j) tv0[j] = TlP[(0 * 4 + lq) * 16 + glb + j * 2];
#pragma unroll
    for (int j = 0; j < 2; ++j) tvA[j] = TlP[(1 * 4 + lq) * 16 + glb + j * 2];
#pragma unroll
    for (int j = 0; j < 2; ++j) {
      bA[j][0] = gload16(K0T + (tv0[j] & 0xFFFFu) * 64 + dlo * 8);
      bA[j][1] = gload16(K0T + (tv0[j] >> 16) * 64 + dlo * 8);
    }
    const char* Ac = (const char*)&As[0][0];
#pragma unroll
    for (int i = 0; i < 4; ++i)
#pragma unroll
      for (int ks = 0; ks < 2; ++ks)
        aA[i][ks] = *(const s16x8*)(Ac + aoff[i][ks]);
  }

  int cur = 0;
  auto iter = [&](int kt, s16x8 (&aC)[4][2], s16x8 (&aN)[4][2],
                  s16x8 (&bC)[2][2], s16x8 (&bN)[2][2],
                  unsigned int (&tvC)[2], unsigned int (&tvN)[2]) {
    // top: drain B(kt) + stage(kt+1) (both issued a full tile ago)
    asm volatile("s_waitcnt vmcnt(0)" ::: "memory");
    __builtin_amdgcn_s_barrier();
    asm volatile("" ::: "memory");
    int nxt = cur + 1; if (nxt >= 3) nxt -= 3;
    if (kt + 2 < NT) {  // tv for tile kt+2 (used next iter)
#pragma unroll
      for (int j = 0; j < 2; ++j)
        tvN[j] = TlP[((kt + 2) * 4 + lq) * 16 + glb + j * 2];
    }
    if (kt + 1 < NT) {
      const char* An = (const char*)&As[nxt][0];
#pragma unroll
      for (int i = 0; i < 4; ++i)   // read A(kt+1), both ks (8 ds_reads)
#pragma unroll
        for (int ks = 0; ks < 2; ++ks)
          aN[i][ks] = *(const s16x8*)(An + aoff[i][ks]);
#pragma unroll
      for (int j = 0; j < 2; ++j) { // issue B(kt+1) via tvC (regs, no LDS dep)
        bN[j][0] = gload16(K0T + (tvC[j] & 0xFFFFu) * 64 + dlo * 8);
        bN[j][1] = gload16(K0T + (tvC[j] >> 16) * 64 + dlo * 8);
      }
      if (kt + 2 < NT) {
        int nb = cur + 2; if (nb >= 3) nb -= 3;  // buf of tile kt-1, free now
        stage(kt + 2, nb);
      }
    }
    __builtin_amdgcn_sched_barrier(0);
    __builtin_amdgcn_s_setprio(1);
#pragma unroll
    for (int ks = 0; ks < 2; ++ks)
#pragma unroll
      for (int i = 0; i < 4; ++i) {
        acc[i][0] = __builtin_amdgcn_mfma_f32_16x16x32_bf16(aC[i][ks], bC[0][ks],
                                                            acc[i][0], 0, 0, 0);
        acc[i][1] = __builtin_amdgcn_mfma_f32_16x16x32_bf16(aC[i][ks], bC[1][ks],
                                                            acc[i][1], 0, 0, 0);
      }
    __builtin_amdgcn_s_setprio(0);
    cur = nxt;
  };

  for (int kt2 = 0; kt2 < NT; kt2 += 2) {  // NT=64 even
    iter(kt2,     aA, aB, bA, bB, tvA, tvB);
    iter(kt2 + 1, aB, aA, bB, bA, tvB, tvA);
  }

  if (POOL == 0) {
    // epilogue: D row = lq*4+r (A-side), col = lr (B-side)  [m89-verified]
#pragma unroll
    for (int i = 0; i < 4; ++i) {
      const int row0 = bm * BM + wm + i * 16 + lq * 4;
#pragma unroll
      for (int j = 0; j < 2; ++j) {
        const int col = bn * 128 + wn + j * 16 + lr;
#pragma unroll
        for (int r = 0; r < 4; ++r) {
          float v = gelu_f(acc[i][j][r] * scale);
          C[(size_t)(row0 + r) * N + col] = f2bf(v);
        }
      }
    }
  } else {
    // fused pool: d = col&7 = lr&7; reduce over j (2 cols) and lr^8 partner
    // (4 g-values per cell), store per-plane partial (each cell once).
    const int plane = bn * 4 + (wn >> 5);
    float* Pp = Ppart + (size_t)plane * 8192;  // [1024][8]
#pragma unroll
    for (int i = 0; i < 4; ++i) {
      const int row0 = bm * BM + wm + i * 16 + lq * 4;
#pragma unroll
      for (int r = 0; r < 4; ++r) {
        float v = gelu_f(acc[i][0][r] * scale) + gelu_f(acc[i][1][r] * scale);
        v += __shfl_xor(v, 8);
        if (lr < 8) Pp[(row0 + r) * 8 + lr] = v * (1.0f / 512.0f);
      }
    }
  }
}

// ---------------- head: sum 128 pool planes + linear ----------------
__global__ __launch_bounds__(256) void k_head(const float* __restrict__ Ppart,
                                              const float* __restrict__ Wamp,
                                              const float* __restrict__ bamp,
                                              const float* __restrict__ Wph,
                                              const float* __restrict__ bph,
                                              float* __restrict__ out,
                                              int out_size) {
  int b = blockIdx.x * 256 + threadIdx.x;  // 1024
  if (b >= 1024) return;
  float acc8[8] = {};
  for (int p = 0; p < 128; ++p) {
    const float* src = Ppart + (size_t)p * 8192 + b * 8;
#pragma unroll
    for (int d = 0; d < 8; ++d) acc8[d] += src[d];
  }
  float a = bamp[0], ph = bph[0];
#pragma unroll
  for (int d = 0; d < 8; ++d) {
    a += acc8[d] * Wamp[d];
    ph += acc8[d] * Wph[d];
  }
  out[b] = a;
  if (out_size >= 2048) out[1024 + b] = ph;
}

// ---------------- launch ----------------

extern "C" void kernel_launch(void* const* d_in, const int* in_sizes, int n_in,
                              void* d_out, int out_size, void* d_ws, size_t ws_size,
                              hipStream_t stream) {
  (void)in_sizes; (void)n_in; (void)ws_size;
  const float* s    = (const float*)d_in[0];
  const int*   perms= (const int*)d_in[1];
  const int*   mult = (const int*)d_in[2];
  const int*   inv  = (const int*)d_in[3];
  const float* Wl   = (const float*)d_in[4];
  const float* bl   = (const float*)d_in[5];
  const float* K0   = (const float*)d_in[6];
  const float* K1   = (const float*)d_in[7];
  const float* Wamp = (const float*)d_in[8];
  const float* bamp = (const float*)d_in[9];
  const float* Wph  = (const float*)d_in[10];
  const float* bph  = (const float*)d_in[11];
  float* out = (float*)d_out;

  // workspace (~22.3 MB):
  //  X1 [0,8M)  X2 [8M,16M)
  //  sb 16M+0..128K  WPT +128K..640K  TallP +640K..1152K
  //  K0T0 +1152K..1216K  K0T1 +1216K..1280K
  //  Ppart [18M, 18M+4M)  (128 x 1024 x 8 f32)
  char* ws = (char*)d_ws;
  unsigned short* X1  = (unsigned short*)(ws);
  unsigned short* X2  = (unsigned short*)(ws + (8u << 20));
  unsigned short* sb  = (unsigned short*)(ws + (16u << 20));
  unsigned short* WPT = (unsigned short*)(ws + (16u << 20) + (128u << 10));
  unsigned int*   TallP=(unsigned int*) (ws + (16u << 20) + (640u << 10));
  unsigned short* K0T0= (unsigned short*)(ws + (16u << 20) + (1152u << 10));
  unsigned short* K0T1= (unsigned short*)(ws + (16u << 20) + (1216u << 10));
  float* Ppart        = (float*)(ws + (18u << 20));

  k_prep<<<1152, 256, 0, stream>>>(s, perms, mult, inv, Wl, K0, K1,
                                   sb, WPT, TallP, K0T0, K0T1);
  // lift: X1 = gelu(s @ W_lift + b_lift), GEMM K=64
  gemm_bf16<<<512, 256, 0, stream>>>(sb, WPT, X1, bl, 1.0f, 1024, 4096, 64);
  gemm_fused<0><<<256, 512, 0, stream>>>(X1, K0T0, TallP, X2, nullptr, SCALE_G);
  gemm_fused<1><<<256, 512, 0, stream>>>(X2, K0T1, TallP, nullptr, Ppart, SCALE_G);
  k_head<<<4, 256, 0, stream>>>(Ppart, Wamp, bamp, Wph, bph, out, out_size);
}

// Round 17
// 108.956 us; speedup vs baseline: 2.6602x; 1.2126x over previous
//
#include <hip/hip_runtime.h>
#include <hip/hip_bf16.h>
#include <cstdint>
#include <cstddef>

using s16x8 = __attribute__((ext_vector_type(8))) short;
using u16x8 = __attribute__((ext_vector_type(8))) unsigned short;
using f32x4 = __attribute__((ext_vector_type(4))) float;

#define GC 4096                        // G * c = 512*8
#define SCALE_G 0.04419417382415922f   // 1/sqrt(512)

__device__ __forceinline__ float gelu_f(float x) {
  float u = 0.7978845608028654f * (x + 0.044715f * x * x * x);
  return 0.5f * x * (1.0f + tanhf(u));
}

// fp32 -> bf16 bits, round-to-nearest-even
__device__ __forceinline__ unsigned short f2bf(float f) {
  unsigned int u = __float_as_uint(f);
  unsigned int r = (u + 0x7fffu + ((u >> 16) & 1u)) >> 16;
  return (unsigned short)r;
}
__device__ __forceinline__ float bf2f(unsigned short b) {
  return __uint_as_float(((unsigned int)b) << 16);
}

// Index arrays may arrive as int32 or int64 (JAX_ENABLE_X64). perms/mult row 0
// are identity [0,1,2,...]: int64 LE high words are 0. Low word suffices.
__device__ __forceinline__ int idx_stride(const int* __restrict__ identity_row) {
  return (identity_row[1] == 0 && identity_row[3] == 0 && identity_row[5] == 0) ? 2 : 1;
}

typedef __attribute__((address_space(1))) void gvoid;
typedef __attribute__((address_space(3))) void lvoid;
__device__ __forceinline__ void gld16(const void* g, void* l) {
  __builtin_amdgcn_global_load_lds((gvoid*)g, (lvoid*)l, 16, 0, 0);
}

// raw 16B global load into VGPRs; NO compiler-tracked wait — caller must
// guard every use behind a manual s_waitcnt vmcnt(N) before consumption.
__device__ __forceinline__ s16x8 gload16(const unsigned short* p) {
  s16x8 r;
  asm volatile("global_load_dwordx4 %0, %1, off" : "=v"(r) : "v"(p));
  return r;
}

// ---------------- fused prep: s->bf16, lift scatter, packed-T table, K^T ----
// TallP[w*512+g] (u32, w = kt*4+lq) = tv(h=kt*8+lq) | tv(h=kt*8+4+lq) << 16,
//   tv(h) = mult[g*512 + inv[h]]   (both ks halves of a K-tile in one word)
// K0T*[tgh*64 + d*8 + c] = bf16(K[tgh*64 + c*8 + d])  (d-major transpose)
__global__ __launch_bounds__(256) void k_prep(
    const float* __restrict__ s, const int* __restrict__ perms,
    const int* __restrict__ mult, const int* __restrict__ inv,
    const float* __restrict__ Wl, const float* __restrict__ K0,
    const float* __restrict__ K1,
    unsigned short* __restrict__ sb, unsigned short* __restrict__ WPT,
    unsigned int* __restrict__ TallP, unsigned short* __restrict__ K0T0,
    unsigned short* __restrict__ K0T1) {
  const int tid = blockIdx.x * 256 + threadIdx.x;
  if (tid < 65536) {                       // s -> bf16
    sb[tid] = f2bf(s[tid]);
  } else if (tid < 98304) {                // lift weight: WPT[(h*8+c)*64+perm]
    const int st = idx_stride(perms);
    const int t2 = tid - 65536;
    const int n = t2 & 63, h = t2 >> 6;
    const int m = perms[(size_t)t2 * st];
#pragma unroll
    for (int c = 0; c < 8; ++c)
      WPT[(size_t)((h << 3) + c) * 64 + m] = f2bf(Wl[n * 8 + c]);
  } else if (tid < 229376) {               // packed T table (131072 words)
    const int st = idx_stride(mult);
    const int i3 = tid - 98304;
    const int g = i3 & 511, w = i3 >> 9;   // w = kt*4 + lq
    const int h0 = (w >> 2) * 8 + (w & 3), h1 = h0 + 4;
    const int ih0 = inv[(size_t)h0 * st], ih1 = inv[(size_t)h1 * st];
    const unsigned int tv0 = (unsigned int)mult[(size_t)((g << 9) + ih0) * st];
    const unsigned int tv1 = (unsigned int)mult[(size_t)((g << 9) + ih1) * st];
    TallP[(size_t)w * 512 + g] = tv0 | (tv1 << 16);
  } else if (tid < 262144) {               // K0 d-transpose -> bf16
    const int t4 = tid - 229376;
    const int tgh = t4 >> 6, e = t4 & 63, d = e >> 3, c = e & 7;
    K0T0[tgh * 64 + d * 8 + c] = f2bf(K0[tgh * 64 + c * 8 + d]);
  } else if (tid < 294912) {               // K1 d-transpose -> bf16
    const int t5 = tid - 262144;
    const int tgh = t5 >> 6, e = t5 & 63, d = e >> 3, c = e & 7;
    K0T1[tgh * 64 + d * 8 + c] = f2bf(K1[tgh * 64 + c * 8 + d]);
  }
}

// ---------------- lift GEMM (K=64): staged-B path ---------------------------
__global__ __launch_bounds__(256) void gemm_bf16(
    const unsigned short* __restrict__ A,   // M x K, row-major bf16
    const unsigned short* __restrict__ BT,  // N x K, row-major bf16 (B^T)
    unsigned short* __restrict__ C,         // M x N bf16 out
    const float* __restrict__ bias8,        // 8 floats indexed by col&7, or null
    float scale, int M, int N, int K) {
  constexpr int BM = 64, BN = 128, BK = 64;
  __shared__ __align__(16) unsigned short As[3][BM * BK];
  __shared__ __align__(16) unsigned short Bs[3][BN * BK];

  const int nbm = M / BM;
  int bid = blockIdx.x;
  {
    const int q = (nbm * (N / BN)) >> 3;
    bid = (bid & 7) * q + (bid >> 3);
  }
  const int bn = bid / nbm, bm = bid % nbm;

  const int t = threadIdx.x;
  const int wid = t >> 6, lane = t & 63;
  const int wm = (wid >> 1) << 5;
  const int wn = (wid & 1) << 6;
  const int lr = lane & 15, lq = lane >> 4;

  const unsigned short* gA[2];
  const unsigned short* gB[4];
#pragma unroll
  for (int is = 0; is < 2; ++is) {
    const int sidx = is * 256 + t, row = sidx >> 3, c = (sidx & 7) ^ (row & 7);
    gA[is] = A + (size_t)(bm * BM + row) * K + c * 8;
  }
#pragma unroll
  for (int is = 0; is < 4; ++is) {
    const int sidx = is * 256 + t, row = sidx >> 3, c = (sidx & 7) ^ (row & 7);
    gB[is] = BT + (size_t)(bn * BN + row) * K + c * 8;
  }

  int aoff[2][2], boff[4][2];
#pragma unroll
  for (int i = 0; i < 2; ++i) {
    const int row = wm + i * 16 + lr;
#pragma unroll
    for (int ks = 0; ks < 2; ++ks)
      aoff[i][ks] = (row * 8 + ((ks * 4 + lq) ^ (row & 7))) * 16;
  }
#pragma unroll
  for (int j = 0; j < 4; ++j) {
    const int row = wn + j * 16 + lr;
#pragma unroll
    for (int ks = 0; ks < 2; ++ks)
      boff[j][ks] = (row * 8 + ((ks * 4 + lq) ^ (row & 7))) * 16;
  }

  auto stage = [&](int kt, int buf) {
    const int koff = kt * BK;
    char* la = (char*)&As[buf][0];
    char* lb = (char*)&Bs[buf][0];
#pragma unroll
    for (int is = 0; is < 2; ++is) gld16(gA[is] + koff, la + (is * 256 + t) * 16);
#pragma unroll
    for (int is = 0; is < 4; ++is) gld16(gB[is] + koff, lb + (is * 256 + t) * 16);
  };

  f32x4 acc[2][4] = {};
  const int nt = K / BK;
  stage(0, 0);
  if (nt > 1) stage(1, 1);

  int cur = 0;
  for (int kt = 0; kt < nt; ++kt) {
    if (kt < nt - 1) asm volatile("s_waitcnt vmcnt(6)" ::: "memory");
    else             asm volatile("s_waitcnt vmcnt(0)" ::: "memory");
    __builtin_amdgcn_s_barrier();
    asm volatile("" ::: "memory");
    __builtin_amdgcn_sched_barrier(0);
    if (kt + 2 < nt) {
      int nb = cur + 2; if (nb >= 3) nb -= 3;
      stage(kt + 2, nb);
    }
    const char* Ac = (const char*)&As[cur][0];
    const char* Bc = (const char*)&Bs[cur][0];
#pragma unroll
    for (int ks = 0; ks < 2; ++ks) {
      s16x8 a0 = *(const s16x8*)(Ac + aoff[0][ks]);
      s16x8 a1 = *(const s16x8*)(Ac + aoff[1][ks]);
      s16x8 b0 = *(const s16x8*)(Bc + boff[0][ks]);
      s16x8 b1 = *(const s16x8*)(Bc + boff[1][ks]);
      s16x8 b2 = *(const s16x8*)(Bc + boff[2][ks]);
      s16x8 b3 = *(const s16x8*)(Bc + boff[3][ks]);
      acc[0][0] = __builtin_amdgcn_mfma_f32_16x16x32_bf16(a0, b0, acc[0][0], 0, 0, 0);
      acc[0][1] = __builtin_amdgcn_mfma_f32_16x16x32_bf16(a0, b1, acc[0][1], 0, 0, 0);
      acc[0][2] = __builtin_amdgcn_mfma_f32_16x16x32_bf16(a0, b2, acc[0][2], 0, 0, 0);
      acc[0][3] = __builtin_amdgcn_mfma_f32_16x16x32_bf16(a0, b3, acc[0][3], 0, 0, 0);
      acc[1][0] = __builtin_amdgcn_mfma_f32_16x16x32_bf16(a1, b0, acc[1][0], 0, 0, 0);
      acc[1][1] = __builtin_amdgcn_mfma_f32_16x16x32_bf16(a1, b1, acc[1][1], 0, 0, 0);
      acc[1][2] = __builtin_amdgcn_mfma_f32_16x16x32_bf16(a1, b2, acc[1][2], 0, 0, 0);
      acc[1][3] = __builtin_amdgcn_mfma_f32_16x16x32_bf16(a1, b3, acc[1][3], 0, 0, 0);
    }
    cur = (cur == 2) ? 0 : cur + 1;
  }

#pragma unroll
  for (int i = 0; i < 2; ++i) {
    const int row0 = bm * BM + wm + i * 16 + lq * 4;
#pragma unroll
    for (int j = 0; j < 4; ++j) {
      const int col = bn * BN + wn + j * 16 + lr;
      const float bv = bias8 ? bias8[col & 7] : 0.0f;
#pragma unroll
      for (int r = 0; r < 4; ++r) {
        float v = gelu_f(acc[i][j][r] * scale + bv);
        C[(size_t)(row0 + r) * N + col] = f2bf(v);
      }
    }
  }
}

// ---------------- fused group-conv GEMM (R11 structure, verbatim) -----------
// Grid 256, 512 thr, 8 waves 2x4, BM=128 BK=64, A 3-buf LDS 48KB + TlP 16KB,
// B per-lane global gather. Per phase:
//   {vmcnt(counted) | barrier | issue ds_read NEXT subtile + issue B/stage
//    | sched_barrier | setprio(1) 8xMFMA on PREVIOUS phase's regs setprio(0)}
// Counted vmcnt: p0-top vmcnt(2) certifies B(kt); p1-top vmcnt(4) certifies
// stage(kt+1). Edges kt=0/NT-1 -> vmcnt(0). (R16 proved vmcnt(0)-per-tile
// regresses: it drains the young stage(kt+1).)
// POOL=0: C = gelu bf16. POOL=1: fused mean-pool -> Ppart[b][plane][8]
// (plane = bn*4 + wn/32; per-cell single writer; 32B contiguous stores).
template <int POOL>
__global__ __launch_bounds__(512, 2) void gemm_fused(
    const unsigned short* __restrict__ A,     // 1024 x 4096 bf16
    const unsigned short* __restrict__ K0T,   // 512 x 64 bf16 (d-major)
    const unsigned int* __restrict__ TallP,   // [kt*4+lq][g] packed u32
    unsigned short* __restrict__ C,           // POOL=0 out
    float* __restrict__ Ppart,                // POOL=1 out [1024][128][8]
    float scale) {
  constexpr int Kdim = 4096, N = 4096, BM = 128, BK = 64, NT = Kdim / BK;
  __shared__ __align__(16) unsigned short As[3][BM * BK];  // 48 KB
  __shared__ __align__(16) unsigned int TlP[64 * 4 * 16];  // 16 KB

  const int bm = blockIdx.x & 7;    // XCD x owns A-panel bm=x (1 MB, L2-fit)
  const int bn = blockIdx.x >> 3;   // 0..31

  const int t = threadIdx.x;               // 0..511
  const int wid = t >> 6, lane = t & 63;
  const int wm = (wid >> 2) << 6;          // 0,64
  const int wn = (wid & 3) << 5;           // 0,32,64,96 (distinct per wave)
  const int lr = lane & 15, lq = lane >> 4;
  const int glb = (wn >> 3) + (lr >> 3);   // block-local g base
  const int dlo = lr & 7;

  // A staging source map (pre-swizzled: LDS slot s holds chunk (s&7)^(row&7))
  const unsigned short* gA[2];
#pragma unroll
  for (int is = 0; is < 2; ++is) {
    const int sidx = is * 512 + t, row = sidx >> 3, c = (sidx & 7) ^ (row & 7);
    gA[is] = A + (size_t)(bm * BM + row) * Kdim + c * 8;
  }
  auto stage = [&](int kt, int buf) {  // 2 gld16 / thread (16 KB tile)
    const int koff = kt * BK;
    char* la = (char*)&As[buf][0];
#pragma unroll
    for (int is = 0; is < 2; ++is) gld16(gA[is] + koff, la + (is * 512 + t) * 16);
  };

  int aoff[4][2];
#pragma unroll
  for (int i = 0; i < 4; ++i) {
    const int row = wm + i * 16 + lr;
#pragma unroll
    for (int ks = 0; ks < 2; ++ks)
      aoff[i][ks] = (row * 8 + ((ks * 4 + lq) ^ (row & 7))) * 16;
  }

  // prologue: stage(0), TlP (2 gld16), stage(1)
  stage(0, 0);
#pragma unroll
  for (int is = 0; is < 2; ++is) {
    const int sidx = is * 512 + t;                  // 0..1023 slots
    const unsigned int* src = TallP + (size_t)(sidx >> 2) * 512 + bn * 16 + (sidx & 3) * 4;
    gld16(src, (char*)&TlP[0] + sidx * 16);
  }
  stage(1, 1);
  asm volatile("s_waitcnt vmcnt(2)" ::: "memory");  // stage(0)+TlP landed
  __builtin_amdgcn_s_barrier();
  asm volatile("" ::: "memory");

  f32x4 acc[4][2] = {};
  s16x8 aE[4], aO[4];          // A-frag double buffer (ks0 / ks1 of cur tile)
  s16x8 bA[2][2], bB[2][2];    // B regs, per-tile parity
  unsigned int tvA[2], tvB[2]; // packed tv, per-tile parity (read 1 tile early)

  // tv(0) fresh + tv(1) into tvA; B(0) into bA; aE <- A(0,ks0)
  {
    unsigned int tv0[2];
#pragma unroll
    for (int j = 0; j < 2; ++j) tv0[j] = TlP[(0 * 4 + lq) * 16 + glb + j * 2];
#pragma unroll
    for (int j = 0; j < 2; ++j) tvA[j] = TlP[(1 * 4 + lq) * 16 + glb + j * 2];
#pragma unroll
    for (int j = 0; j < 2; ++j) {
      bA[j][0] = gload16(K0T + (tv0[j] & 0xFFFFu) * 64 + dlo * 8);
      bA[j][1] = gload16(K0T + (tv0[j] >> 16) * 64 + dlo * 8);
    }
    const char* Ac = (const char*)&As[0][0];
#pragma unroll
    for (int i = 0; i < 4; ++i) aE[i] = *(const s16x8*)(Ac + aoff[i][0]);
  }

  int cur = 0;
  auto iter = [&](int kt, s16x8 (&bu)[2][2], s16x8 (&bp)[2][2],
                  unsigned int (&tvu)[2], unsigned int (&tvn)[2]) {
    const char* Ac = (const char*)&As[cur][0];
    int nxt = cur + 1; if (nxt >= 3) nxt -= 3;
    const char* An = (const char*)&As[nxt][0];
    // ---------------- phase 0 ----------------
    if (kt == 0 || kt == NT - 1) asm volatile("s_waitcnt vmcnt(0)" ::: "memory");
    else                         asm volatile("s_waitcnt vmcnt(2)" ::: "memory");
    __builtin_amdgcn_s_barrier();
    asm volatile("" ::: "memory");
    if (kt + 2 < NT) {  // tv for tile kt+2 (used next iter)
#pragma unroll
      for (int j = 0; j < 2; ++j)
        tvn[j] = TlP[((kt + 2) * 4 + lq) * 16 + glb + j * 2];
    }
#pragma unroll
    for (int i = 0; i < 4; ++i) aO[i] = *(const s16x8*)(Ac + aoff[i][1]);
    if (kt + 1 < NT) {  // B(kt+1) via tvu (register, no LDS wait)
#pragma unroll
      for (int j = 0; j < 2; ++j) {
        bp[j][0] = gload16(K0T + (tvu[j] & 0xFFFFu) * 64 + dlo * 8);
        bp[j][1] = gload16(K0T + (tvu[j] >> 16) * 64 + dlo * 8);
      }
    }
    __builtin_amdgcn_sched_barrier(0);
    __builtin_amdgcn_s_setprio(1);
    acc[0][0] = __builtin_amdgcn_mfma_f32_16x16x32_bf16(aE[0], bu[0][0], acc[0][0], 0, 0, 0);
    acc[0][1] = __builtin_amdgcn_mfma_f32_16x16x32_bf16(aE[0], bu[1][0], acc[0][1], 0, 0, 0);
    acc[1][0] = __builtin_amdgcn_mfma_f32_16x16x32_bf16(aE[1], bu[0][0], acc[1][0], 0, 0, 0);
    acc[1][1] = __builtin_amdgcn_mfma_f32_16x16x32_bf16(aE[1], bu[1][0], acc[1][1], 0, 0, 0);
    acc[2][0] = __builtin_amdgcn_mfma_f32_16x16x32_bf16(aE[2], bu[0][0], acc[2][0], 0, 0, 0);
    acc[2][1] = __builtin_amdgcn_mfma_f32_16x16x32_bf16(aE[2], bu[1][0], acc[2][1], 0, 0, 0);
    acc[3][0] = __builtin_amdgcn_mfma_f32_16x16x32_bf16(aE[3], bu[0][0], acc[3][0], 0, 0, 0);
    acc[3][1] = __builtin_amdgcn_mfma_f32_16x16x32_bf16(aE[3], bu[1][0], acc[3][1], 0, 0, 0);
    __builtin_amdgcn_s_setprio(0);
    // ---------------- phase 1 ----------------
    if (kt < NT - 1) asm volatile("s_waitcnt vmcnt(4)" ::: "memory");
    else             asm volatile("s_waitcnt vmcnt(0)" ::: "memory");
    __builtin_amdgcn_s_barrier();
    asm volatile("" ::: "memory");
    if (kt + 1 < NT) {  // aE <- A(kt+1, ks0); stage tile kt+2
#pragma unroll
      for (int i = 0; i < 4; ++i) aE[i] = *(const s16x8*)(An + aoff[i][0]);
      if (kt + 2 < NT) {
        int nb = cur + 2; if (nb >= 3) nb -= 3;  // buf of tile kt-1, free now
        stage(kt + 2, nb);
      }
    }
    __builtin_amdgcn_sched_barrier(0);
    __builtin_amdgcn_s_setprio(1);
    acc[0][0] = __builtin_amdgcn_mfma_f32_16x16x32_bf16(aO[0], bu[0][1], acc[0][0], 0, 0, 0);
    acc[0][1] = __builtin_amdgcn_mfma_f32_16x16x32_bf16(aO[0], bu[1][1], acc[0][1], 0, 0, 0);
    acc[1][0] = __builtin_amdgcn_mfma_f32_16x16x32_bf16(aO[1], bu[0][1], acc[1][0], 0, 0, 0);
    acc[1][1] = __builtin_amdgcn_mfma_f32_16x16x32_bf16(aO[1], bu[1][1], acc[1][1], 0, 0, 0);
    acc[2][0] = __builtin_amdgcn_mfma_f32_16x16x32_bf16(aO[2], bu[0][1], acc[2][0], 0, 0, 0);
    acc[2][1] = __builtin_amdgcn_mfma_f32_16x16x32_bf16(aO[2], bu[1][1], acc[2][1], 0, 0, 0);
    acc[3][0] = __builtin_amdgcn_mfma_f32_16x16x32_bf16(aO[3], bu[0][1], acc[3][0], 0, 0, 0);
    acc[3][1] = __builtin_amdgcn_mfma_f32_16x16x32_bf16(aO[3], bu[1][1], acc[3][1], 0, 0, 0);
    __builtin_amdgcn_s_setprio(0);
    cur = nxt;
  };

  for (int kt2 = 0; kt2 < NT; kt2 += 2) {  // NT=64 even
    iter(kt2, bA, bB, tvA, tvB);
    iter(kt2 + 1, bB, bA, tvB, tvA);
  }

  if (POOL == 0) {
    // epilogue: D row = lq*4+r (A-side), col = lr (B-side)  [m89-verified]
#pragma unroll
    for (int i = 0; i < 4; ++i) {
      const int row0 = bm * BM + wm + i * 16 + lq * 4;
#pragma unroll
      for (int j = 0; j < 2; ++j) {
        const int col = bn * 128 + wn + j * 16 + lr;
#pragma unroll
        for (int r = 0; r < 4; ++r) {
          float v = gelu_f(acc[i][j][r] * scale);
          C[(size_t)(row0 + r) * N + col] = f2bf(v);
        }
      }
    }
  } else {
    // fused pool: d = col&7 = lr&7; reduce over j (2 cols) and lr^8 partner
    // (4 g-values); store partial to Ppart[b][plane][d] (each cell once;
    // 8 lanes -> one 32B contiguous store).
    const int plane = bn * 4 + (wn >> 5);
#pragma unroll
    for (int i = 0; i < 4; ++i) {
      const int row0 = bm * BM + wm + i * 16 + lq * 4;
#pragma unroll
      for (int r = 0; r < 4; ++r) {
        float v = gelu_f(acc[i][0][r] * scale) + gelu_f(acc[i][1][r] * scale);
        v += __shfl_xor(v, 8);
        if (lr < 8)
          Ppart[((size_t)(row0 + r) * 128 + plane) * 8 + lr] = v * (1.0f / 512.0f);
      }
    }
  }
}

// ---------------- head: per-b parallel plane reduction + linear -------------
// grid 1024 (one block per b), 128 threads: thread t reads plane t's 8 floats
// (contiguous 32B, coalesced across threads), LDS-reduce, dot with W.
__global__ __launch_bounds__(128) void k_head(const float* __restrict__ Ppart,
                                              const float* __restrict__ Wamp,
                                              const float* __restrict__ bamp,
                                              const float* __restrict__ Wph,
                                              const float* __restrict__ bph,
                                              float* __restrict__ out,
                                              int out_size) {
  __shared__ float red[128 * 8];
  const int b = blockIdx.x, t = threadIdx.x;
  const float* src = Ppart + ((size_t)b * 128 + t) * 8;
  f32x4 v0 = *(const f32x4*)(src);
  f32x4 v1 = *(const f32x4*)(src + 4);
  *(f32x4*)(red + t * 8) = v0;
  *(f32x4*)(red + t * 8 + 4) = v1;
  __syncthreads();
  if (t < 8) {
    float s = 0.f;
#pragma unroll 16
    for (int p = 0; p < 128; ++p) s += red[p * 8 + t];
    red[1024 + t] = s;
  }
  __syncthreads();
  if (t == 0) {
    float a = bamp[0], ph = bph[0];
#pragma unroll
    for (int d = 0; d < 8; ++d) {
      a += red[1024 + d] * Wamp[d];
      ph += red[1024 + d] * Wph[d];
    }
    out[b] = a;
    if (out_size >= 2048) out[1024 + b] = ph;
  }
}

// ---------------- launch ----------------

extern "C" void kernel_launch(void* const* d_in, const int* in_sizes, int n_in,
                              void* d_out, int out_size, void* d_ws, size_t ws_size,
                              hipStream_t stream) {
  (void)in_sizes; (void)n_in; (void)ws_size;
  const float* s    = (const float*)d_in[0];
  const int*   perms= (const int*)d_in[1];
  const int*   mult = (const int*)d_in[2];
  const int*   inv  = (const int*)d_in[3];
  const float* Wl   = (const float*)d_in[4];
  const float* bl   = (const float*)d_in[5];
  const float* K0   = (const float*)d_in[6];
  const float* K1   = (const float*)d_in[7];
  const float* Wamp = (const float*)d_in[8];
  const float* bamp = (const float*)d_in[9];
  const float* Wph  = (const float*)d_in[10];
  const float* bph  = (const float*)d_in[11];
  float* out = (float*)d_out;

  // workspace (~22.3 MB):
  //  X1 [0,8M)  X2 [8M,16M)
  //  sb 16M+0..128K  WPT +128K..640K  TallP +640K..1152K
  //  K0T0 +1152K..1216K  K0T1 +1216K..1280K
  //  Ppart [18M, 18M+4M)  (1024 x 128 x 8 f32)
  char* ws = (char*)d_ws;
  unsigned short* X1  = (unsigned short*)(ws);
  unsigned short* X2  = (unsigned short*)(ws + (8u << 20));
  unsigned short* sb  = (unsigned short*)(ws + (16u << 20));
  unsigned short* WPT = (unsigned short*)(ws + (16u << 20) + (128u << 10));
  unsigned int*   TallP=(unsigned int*) (ws + (16u << 20) + (640u << 10));
  unsigned short* K0T0= (unsigned short*)(ws + (16u << 20) + (1152u << 10));
  unsigned short* K0T1= (unsigned short*)(ws + (16u << 20) + (1216u << 10));
  float* Ppart        = (float*)(ws + (18u << 20));

  k_prep<<<1152, 256, 0, stream>>>(s, perms, mult, inv, Wl, K0, K1,
                                   sb, WPT, TallP, K0T0, K0T1);
  // lift: X1 = gelu(s @ W_lift + b_lift), GEMM K=64
  gemm_bf16<<<512, 256, 0, stream>>>(sb, WPT, X1, bl, 1.0f, 1024, 4096, 64);
  gemm_fused<0><<<256, 512, 0, stream>>>(X1, K0T0, TallP, X2, nullptr, SCALE_G);
  gemm_fused<1><<<256, 512, 0, stream>>>(X2, K0T1, TallP, nullptr, Ppart, SCALE_G);
  k_head<<<1024, 128, 0, stream>>>(Ppart, Wamp, bamp, Wph, bph, out, out_size);
}